// Round 1
// baseline (462.601 us; speedup 1.0000x reference)
//
#include <hip/hip_runtime.h>

// out[s,:] = mean_{e: sid[e]==s} vals[gidx[e],:], D=64 fp32, sids sorted.
//
// R1 (this round): K=2 segments per wave, merged contiguous edge range.
//   - One scalarized starts fetch (readfirstlane -> s_load) per wave instead
//     of one vector starts fetch per segment: halves the dependent
//     starts->gidx->gather chains per unit work.
//   - One gidx chunk load covers both segments; the 2-3 unrolled 16-edge
//     passes put 8-12 independent dwordx4 gathers in flight (vs 4).
//   - Segment attribution is branchless: dual accumulators with float masks
//     from (e >= b1-cb). Invalid slots get mask 0 (subsumes the old
//     remainder path, removing its duplicated clamped loads).
//   - Tail: shfl-xor reduce over lane bits 4,5 for BOTH accs; subgroup 0
//     stores seg0's row, subgroup 1 stores seg1's row (parallel NT stores).
//
// Wave layout: lane = (sub, c): sub=lane>>4 -> one of 4 edges per load inst,
// c=lane&15 -> float4 column. One dwordx4 load = 4 full 256B rows = 4 edges.
// ROW STRIDE = 64 floats * 4B = 256B -> byte offset is idx<<8.
// Streaming data (gidx, out) uses non-temporal hints so the 256MB table keeps
// the 256MB L3; table loads stay cached (4x average reuse).
#define D 64

// Native vector type: __builtin_nontemporal_* requires scalar/native-vector,
// not HIP's struct-based float4.
typedef float vfloat4 __attribute__((ext_vector_type(4)));

// starts[s] = first edge index with sids[e] >= s, s in [0, nseg].
__global__ __launch_bounds__(256) void seg_starts_kernel(
    const int* __restrict__ sids, int E, int nseg, int* __restrict__ starts) {
    int e = blockIdx.x * blockDim.x + threadIdx.x;
    if (e >= E) return;
    int cur = __builtin_nontemporal_load(&sids[e]);
    int prev = (e == 0) ? -1 : __builtin_nontemporal_load(&sids[e - 1]);
    for (int s = prev + 1; s <= cur; ++s) starts[s] = e;
    if (e == E - 1) {
        for (int s = cur + 1; s <= nseg; ++s) starts[s] = E;
    }
}

// One wave per TWO consecutive segments. starts==nullptr -> in-kernel binary
// search fallback (only when ws_size can't hold the starts array).
__global__ __launch_bounds__(256) void seg_mean_kernel(
    const float* __restrict__ vals, const int* __restrict__ gidx,
    const int* __restrict__ sids, const int* __restrict__ starts,
    float* __restrict__ out, int E, int nseg) {
    int lane = threadIdx.x & 63;
    int wid = blockIdx.x * (blockDim.x >> 6) + (threadIdx.x >> 6);
    int s0 = wid << 1;
    if (s0 >= nseg) return;
    // s0 is wave-uniform; force SGPR so starts loads become s_load (scalar
    // path, issued in parallel, off the vector-memory port).
    int s0u = __builtin_amdgcn_readfirstlane(s0);
    int sTop = s0u + 2; if (sTop > nseg) sTop = nseg;

    int b0, b1, b2;   // edge range [b0,b1) -> seg s0, [b1,b2) -> seg s0+1
    if (starts) {
        b0 = starts[s0u];
        b1 = starts[s0u + 1];
        b2 = starts[sTop];
    } else {
        int lo = 0, hi = E;
        while (lo < hi) { int m = (lo + hi) >> 1; if (sids[m] < s0u) lo = m + 1; else hi = m; }
        b0 = lo;
        lo = b0; hi = E;
        while (lo < hi) { int m = (lo + hi) >> 1; if (sids[m] < s0u + 1) lo = m + 1; else hi = m; }
        b1 = lo;
        lo = b1; hi = E;
        while (lo < hi) { int m = (lo + hi) >> 1; if (sids[m] < sTop) lo = m + 1; else hi = m; }
        b2 = lo;
    }

    int sub = lane >> 4;          // edge subgroup 0..3
    int c16 = (lane & 15) << 4;   // float4 column byte offset 0..240

    const char* vbase = (const char*)vals;  // 256MB table: 32-bit byte offsets fit
    vfloat4 acc0 = {0,0,0,0}, acc1 = {0,0,0,0};

    for (int cb = b0; cb < b2; cb += 64) {
        int n = b2 - cb;              // uniform (SGPR): chunk valid count
        if (n > 64) n = 64;
        int t1 = b1 - cb;             // local boundary: e >= t1 -> segment 1
        // Coalesced idx load, clamped (branchless).
        int l = (lane < n) ? lane : (n - 1);
        int my = __builtin_nontemporal_load(&gidx[cb + l]);

        #pragma unroll
        for (int j = 0; j < 64; j += 16) {
            if (j < n) {   // uniform branch (n is SGPR) — skips empty passes
                int e0 = j + sub, e1 = j + 4 + sub, e2 = j + 8 + sub, e3 = j + 12 + sub;
                int q0 = (e0 < n) ? e0 : (n - 1);
                int q1 = (e1 < n) ? e1 : (n - 1);
                int q2 = (e2 < n) ? e2 : (n - 1);
                int q3 = (e3 < n) ? e3 : (n - 1);
                int i0 = __shfl(my, q0, 64);
                int i1 = __shfl(my, q1, 64);
                int i2 = __shfl(my, q2, 64);
                int i3 = __shfl(my, q3, 64);
                vfloat4 v0 = *(const vfloat4*)(vbase + (((unsigned)i0 << 8) | c16));
                vfloat4 v1 = *(const vfloat4*)(vbase + (((unsigned)i1 << 8) | c16));
                vfloat4 v2 = *(const vfloat4*)(vbase + (((unsigned)i2 << 8) | c16));
                vfloat4 v3 = *(const vfloat4*)(vbase + (((unsigned)i3 << 8) | c16));
                // Branchless dual-segment attribution: w = valid, z = valid & seg1.
                float w0 = (e0 < n) ? 1.0f : 0.0f, z0 = (e0 < n && e0 >= t1) ? 1.0f : 0.0f;
                float w1 = (e1 < n) ? 1.0f : 0.0f, z1 = (e1 < n && e1 >= t1) ? 1.0f : 0.0f;
                float w2 = (e2 < n) ? 1.0f : 0.0f, z2 = (e2 < n && e2 >= t1) ? 1.0f : 0.0f;
                float w3 = (e3 < n) ? 1.0f : 0.0f, z3 = (e3 < n && e3 >= t1) ? 1.0f : 0.0f;
                acc0 += v0 * (w0 - z0); acc1 += v0 * z0;
                acc0 += v1 * (w1 - z1); acc1 += v1 * z1;
                acc0 += v2 * (w2 - z2); acc1 += v2 * z2;
                acc0 += v3 * (w3 - z3); acc1 += v3 * z3;
            }
        }
    }

    // Reduce both accumulators across the 4 edge subgroups (lane bits 4,5).
    acc0.x += __shfl_xor(acc0.x, 16, 64); acc0.y += __shfl_xor(acc0.y, 16, 64);
    acc0.z += __shfl_xor(acc0.z, 16, 64); acc0.w += __shfl_xor(acc0.w, 16, 64);
    acc0.x += __shfl_xor(acc0.x, 32, 64); acc0.y += __shfl_xor(acc0.y, 32, 64);
    acc0.z += __shfl_xor(acc0.z, 32, 64); acc0.w += __shfl_xor(acc0.w, 32, 64);
    acc1.x += __shfl_xor(acc1.x, 16, 64); acc1.y += __shfl_xor(acc1.y, 16, 64);
    acc1.z += __shfl_xor(acc1.z, 16, 64); acc1.w += __shfl_xor(acc1.w, 16, 64);
    acc1.x += __shfl_xor(acc1.x, 32, 64); acc1.y += __shfl_xor(acc1.y, 32, 64);
    acc1.z += __shfl_xor(acc1.z, 32, 64); acc1.w += __shfl_xor(acc1.w, 32, 64);

    int cnt0 = b1 - b0, cnt1 = b2 - b1;
    if (sub == 0) {
        float inv = 1.0f / (float)((cnt0 > 0) ? cnt0 : 1);
        vfloat4 r = acc0 * inv;
        // 16 lanes x 16B = one 256B out row; NT store: written once, never read.
        __builtin_nontemporal_store(r, (vfloat4*)((char*)out + (((unsigned)s0 << 8) | c16)));
    } else if (sub == 1 && s0 + 1 < nseg) {
        float inv = 1.0f / (float)((cnt1 > 0) ? cnt1 : 1);
        vfloat4 r = acc1 * inv;
        __builtin_nontemporal_store(r, (vfloat4*)((char*)out + (((unsigned)(s0 + 1) << 8) | c16)));
    }
}

extern "C" void kernel_launch(void* const* d_in, const int* in_sizes, int n_in,
                              void* d_out, int out_size, void* d_ws, size_t ws_size,
                              hipStream_t stream) {
    const float* vals = (const float*)d_in[0];   // [N_SRC, 64] fp32
    const int*   gidx = (const int*)d_in[1];     // [E] int32
    const int*   sids = (const int*)d_in[2];     // [E] int32, sorted
    float*       out  = (float*)d_out;           // [nseg, 64] fp32

    int E = in_sizes[1];
    int nseg = out_size / D;

    int* starts = nullptr;
    size_t need = (size_t)(nseg + 1) * sizeof(int);
    if (ws_size >= need) {
        starts = (int*)d_ws;
        int blocks = (E + 255) / 256;
        seg_starts_kernel<<<blocks, 256, 0, stream>>>(sids, E, nseg, starts);
    }

    const int waves_per_block = 4;
    int waves = (nseg + 1) >> 1;                 // 2 segments per wave
    int blocks2 = (waves + waves_per_block - 1) / waves_per_block;
    seg_mean_kernel<<<blocks2, waves_per_block * 64, 0, stream>>>(
        vals, gidx, sids, starts, out, E, nseg);
}